// Round 10
// baseline (252.781 us; speedup 1.0000x reference)
//
#include <hip/hip_runtime.h>
#include <hip/hip_bf16.h>

#define NHEADS 12
#define HDIM 64
#define BATCH 2
#define SEQ 2048
#define DMODEL 768
#define MROWS (BATCH * SEQ)   // 4096

typedef __bf16  bf16x8 __attribute__((ext_vector_type(8)));
typedef float   f32x4  __attribute__((ext_vector_type(4)));

__device__ inline unsigned short to_bf16(float f) {
    union { float f; unsigned u; } x; x.f = f;
    const unsigned r = x.u + 0x7FFFu + ((x.u >> 16) & 1u);   // RNE
    return (unsigned short)(r >> 16);
}
__device__ inline unsigned pack_bf16x2(float a, float b) {
    const __hip_bfloat162 h = __float22bfloat162_rn(float2{a, b});
    union { __hip_bfloat162 h; unsigned u; } c; c.h = h; return c.u;
}

// async global->LDS, 16B per lane, dest = wave-uniform base + lane*16
#define GLDS16(gsrc, ldst)                                                    \
    __builtin_amdgcn_global_load_lds(                                         \
        (const __attribute__((address_space(1))) void*)(gsrc),                \
        (__attribute__((address_space(3))) void*)(ldst), 16, 0, 0)

// ---------------------------------------------------------------------------
// cvt_all: one dispatch for (a) x fp32->bf16 and (b) 4x W transpose+cast.
// blocks [0, 3072): x convert (n4 = 786432 = 3072*256 exactly).
// blocks [3072, 5376): W transpose, z = (bid-3072)/576, 24x24 tiles.
// ---------------------------------------------------------------------------
__global__ __launch_bounds__(256) void cvt_all(const float* __restrict__ x,
                                               const float* __restrict__ Wq,
                                               const float* __restrict__ Wk,
                                               const float* __restrict__ Wv,
                                               const float* __restrict__ Wo,
                                               unsigned short* __restrict__ x_bf,
                                               unsigned short* __restrict__ wt_all,
                                               unsigned short* __restrict__ wot) {
    __shared__ float tile[32][33];
    const int bid = blockIdx.x;
    if (bid < 3072) {
        const int i = bid * 256 + threadIdx.x;
        const float4 v = reinterpret_cast<const float4*>(x)[i];
        ushort4 o;
        o.x = to_bf16(v.x); o.y = to_bf16(v.y);
        o.z = to_bf16(v.z); o.w = to_bf16(v.w);
        reinterpret_cast<ushort4*>(x_bf)[i] = o;
        return;
    }
    const int wz = bid - 3072;
    const int z = wz / 576, r2 = wz % 576;
    const int bx = r2 % 24, by = r2 / 24;
    const float* W = (z == 0) ? Wq : (z == 1) ? Wk : (z == 2) ? Wv : Wo;
    unsigned short* out = (z < 3) ? (wt_all + (size_t)z * DMODEL * DMODEL) : wot;

    const int tx = threadIdx.x & 31, ty = threadIdx.x >> 5;
    const int nbase = bx * 32, kbase = by * 32;

    #pragma unroll
    for (int p = 0; p < 4; ++p) {
        const int r = ty + p * 8;
        tile[r][tx] = W[(size_t)(kbase + r) * DMODEL + nbase + tx];
    }
    __syncthreads();
    #pragma unroll
    for (int p = 0; p < 4; ++p) {
        const int r = ty + p * 8;
        out[(size_t)(nbase + r) * DMODEL + kbase + tx] = to_bf16(tile[tx][r]);
    }
}

// ---------------------------------------------------------------------------
// Fused QKV GEMM: A (4096 x 768 bf16) @ Wt^T (Wt: 2304 x 768 bf16 [n][k]).
// seg = n/768 selects {Q scatter (B,H,S,hd), K scatter, V^T scatter (B,H,hd,S)}.
// Q segment scaled by 0.125. 128x128 tile, BK=32, 4 waves.
// ---------------------------------------------------------------------------
__global__ __launch_bounds__(256) void gemm_qkv(const unsigned short* __restrict__ A,
                                                const unsigned short* __restrict__ Wt,
                                                const float* __restrict__ bq,
                                                const float* __restrict__ bk,
                                                const float* __restrict__ bv,
                                                unsigned short* __restrict__ q_bf,
                                                unsigned short* __restrict__ k_bf,
                                                unsigned short* __restrict__ vt_bf) {
    constexpr int K = DMODEL;
    __shared__ unsigned short As[128 * 32];
    __shared__ unsigned short Bs[128 * 32];

    const int t = threadIdx.x;
    const int lane = t & 63;
    const int w = t >> 6, wr = w >> 1, wc = w & 1;
    const int m0 = blockIdx.y * 128, n0 = blockIdx.x * 128;
    const int lr = lane & 15;
    const int kg = lane >> 4;

    const int row0 = t >> 2,        cp0 = t & 3;
    const int row1 = (t + 256) >> 2, cp1 = t & 3;
    const int c0 = cp0 ^ ((row0 >> 1) & 3);
    const int c1 = cp1 ^ ((row1 >> 1) & 3);
    unsigned short* asd0 = &As[(w * 64) * 8];
    unsigned short* asd1 = &As[(256 + w * 64) * 8];
    unsigned short* bsd0 = &Bs[(w * 64) * 8];
    unsigned short* bsd1 = &Bs[(256 + w * 64) * 8];

    f32x4 acc[4][4] = {};

    for (int k0 = 0; k0 < K; k0 += 32) {
        GLDS16(A  + (size_t)(m0 + row0) * K + k0 + c0 * 8, asd0);
        GLDS16(A  + (size_t)(m0 + row1) * K + k0 + c1 * 8, asd1);
        GLDS16(Wt + (size_t)(n0 + row0) * K + k0 + c0 * 8, bsd0);
        GLDS16(Wt + (size_t)(n0 + row1) * K + k0 + c1 * 8, bsd1);
        __syncthreads();

        bf16x8 af[4], bfr[4];
        #pragma unroll
        for (int i = 0; i < 4; ++i) {
            const int ar = wr * 64 + i * 16 + lr;
            af[i] = *reinterpret_cast<const bf16x8*>(
                &As[ar * 32 + ((kg ^ ((ar >> 1) & 3)) * 8)]);
            const int br = wc * 64 + i * 16 + lr;
            bfr[i] = *reinterpret_cast<const bf16x8*>(
                &Bs[br * 32 + ((kg ^ ((br >> 1) & 3)) * 8)]);
        }
        #pragma unroll
        for (int i = 0; i < 4; ++i)
            #pragma unroll
            for (int j = 0; j < 4; ++j)
                acc[i][j] = __builtin_amdgcn_mfma_f32_16x16x32_bf16(
                    af[i], bfr[j], acc[i][j], 0, 0, 0);
        __syncthreads();
    }

    // epilogue: seg is block-uniform (768 % 128 == 0)
    const int seg = n0 / DMODEL;
    const float scale = (seg == 0) ? 0.125f : 1.0f;
    const float* bias = (seg == 0) ? bq : (seg == 1) ? bk : bv;
    const int mb = m0 + wr * 64, nb = n0 - seg * DMODEL + wc * 64;

    #pragma unroll
    for (int i = 0; i < 4; ++i) {
        #pragma unroll
        for (int j = 0; j < 4; ++j) {
            const int cl = nb + j * 16 + lr;       // column within matrix
            const float bv_ = bias[cl];
            const int h = cl >> 6, d = cl & (HDIM - 1);
            if (seg < 2) {
                unsigned short* dst = (seg == 0) ? q_bf : k_bf;
                #pragma unroll
                for (int q = 0; q < 4; ++q) {
                    const int row = mb + i * 16 + kg * 4 + q;
                    const int b = row >> 11, s = row & (SEQ - 1);
                    dst[(((size_t)(b * NHEADS + h)) * SEQ + s) * HDIM + d] =
                        to_bf16((acc[i][j][q] + bv_) * scale);
                }
            } else {
                ushort4 pk;
                #pragma unroll
                for (int q = 0; q < 4; ++q)
                    ((unsigned short*)&pk)[q] = to_bf16(acc[i][j][q] + bv_);
                const int r0 = mb + i * 16 + kg * 4;
                const int b = r0 >> 11, s = r0 & (SEQ - 1);
                *reinterpret_cast<ushort4*>(
                    &vt_bf[(((size_t)(b * NHEADS + h)) * HDIM + d) * SEQ + s]) = pk;
            }
        }
    }
}

// ---------------------------------------------------------------------------
// Out-projection GEMM: C = A (4096 x 768 bf16) @ Wo^T + bo, fp32 row-major.
// ---------------------------------------------------------------------------
__global__ __launch_bounds__(256) void gemm_out(const unsigned short* __restrict__ A,
                                                const unsigned short* __restrict__ Bt,
                                                const float* __restrict__ bias,
                                                float* __restrict__ out) {
    constexpr int K = DMODEL;
    __shared__ unsigned short As[128 * 32];
    __shared__ unsigned short Bs[128 * 32];

    const int t = threadIdx.x;
    const int lane = t & 63;
    const int w = t >> 6, wr = w >> 1, wc = w & 1;
    const int m0 = blockIdx.y * 128, n0 = blockIdx.x * 128;
    const int lr = lane & 15;
    const int kg = lane >> 4;

    const int row0 = t >> 2,        cp0 = t & 3;
    const int row1 = (t + 256) >> 2, cp1 = t & 3;
    const int c0 = cp0 ^ ((row0 >> 1) & 3);
    const int c1 = cp1 ^ ((row1 >> 1) & 3);
    unsigned short* asd0 = &As[(w * 64) * 8];
    unsigned short* asd1 = &As[(256 + w * 64) * 8];
    unsigned short* bsd0 = &Bs[(w * 64) * 8];
    unsigned short* bsd1 = &Bs[(256 + w * 64) * 8];

    f32x4 acc[4][4] = {};

    for (int k0 = 0; k0 < K; k0 += 32) {
        GLDS16(A  + (size_t)(m0 + row0) * K + k0 + c0 * 8, asd0);
        GLDS16(A  + (size_t)(m0 + row1) * K + k0 + c1 * 8, asd1);
        GLDS16(Bt + (size_t)(n0 + row0) * K + k0 + c0 * 8, bsd0);
        GLDS16(Bt + (size_t)(n0 + row1) * K + k0 + c1 * 8, bsd1);
        __syncthreads();

        bf16x8 af[4], bfr[4];
        #pragma unroll
        for (int i = 0; i < 4; ++i) {
            const int ar = wr * 64 + i * 16 + lr;
            af[i] = *reinterpret_cast<const bf16x8*>(
                &As[ar * 32 + ((kg ^ ((ar >> 1) & 3)) * 8)]);
            const int br = wc * 64 + i * 16 + lr;
            bfr[i] = *reinterpret_cast<const bf16x8*>(
                &Bs[br * 32 + ((kg ^ ((br >> 1) & 3)) * 8)]);
        }
        #pragma unroll
        for (int i = 0; i < 4; ++i)
            #pragma unroll
            for (int j = 0; j < 4; ++j)
                acc[i][j] = __builtin_amdgcn_mfma_f32_16x16x32_bf16(
                    af[i], bfr[j], acc[i][j], 0, 0, 0);
        __syncthreads();
    }

    const int mb = m0 + wr * 64, nb = n0 + wc * 64;
    #pragma unroll
    for (int i = 0; i < 4; ++i) {
        #pragma unroll
        for (int j = 0; j < 4; ++j) {
            const int col = nb + j * 16 + lr;
            const float bv = bias[col];
            #pragma unroll
            for (int q = 0; q < 4; ++q) {
                const int row = mb + i * 16 + kg * 4 + q;
                out[(size_t)row * DMODEL + col] = acc[i][j][q] + bv;
            }
        }
    }
}

// ---------------------------------------------------------------------------
// MFMA flash attention v2. Grid (SEQ/64, B*H), 128 threads = 2 waves.
// Each wave owns 32 q-rows (2 fragment rows) -> K fragment reads amortized
// over 2 q-streams. K staged in padded LDS; V^T fragments read DIRECT from
// global (L1/L2-resident; issued early each tile, consumed after softmax).
// l via ones-MFMA; P packed with v_cvt_pk_bf16_f32; P LDS is wave-private.
// ---------------------------------------------------------------------------
__global__ __launch_bounds__(128) void flash_mfma(
        const unsigned short* __restrict__ Qg,
        const unsigned short* __restrict__ Kgl,
        const unsigned short* __restrict__ Vtg,
        unsigned short* __restrict__ Cctx) {
    __shared__ __align__(16) unsigned short k_s[64 * 72];
    __shared__ __align__(16) unsigned short p_s[2 * 32 * 72];

    const int t = threadIdx.x;
    const int lane = t & 63, w = t >> 6;          // w in {0,1}
    const int lr = lane & 15, kg = lane >> 4;
    const int qb = blockIdx.x, bh = blockIdx.y;
    const size_t sbase = (size_t)bh * SEQ * HDIM;   // Q/K: (B,H,S,hd)
    const size_t vtb   = (size_t)bh * HDIM * SEQ;   // Vt:  (B,H,hd,S)

    // Q fragments: wave w covers q-rows q0..q0+31 as two 16-row streams
    const int q0 = qb * 64 + w * 32;
    bf16x8 qf[2][2];
    #pragma unroll
    for (int qs = 0; qs < 2; ++qs)
        #pragma unroll
        for (int h2 = 0; h2 < 2; ++h2)
            qf[qs][h2] = *reinterpret_cast<const bf16x8*>(
                &Qg[sbase + (size_t)(q0 + qs * 16 + lr) * HDIM + h2 * 32 + kg * 8]);

    bf16x8 ones;
    #pragma unroll
    for (int i = 0; i < 8; ++i) ones[i] = (__bf16)1.0f;

    // K staging: thread covers row sr, 64B half h4 (4 x 16B chunks)
    const int sr = t & 63, h4 = t >> 6;

    uint4 kr[4];
    #pragma unroll
    for (int c = 0; c < 4; ++c)
        kr[c] = *reinterpret_cast<const uint4*>(
            &Kgl[sbase + (size_t)sr * HDIM + h4 * 32 + c * 8]);

    f32x4 oa[2][4] = {};
    f32x4 l_acc[2] = {};
    float m_run[2][4] = {{-1e30f, -1e30f, -1e30f, -1e30f},
                         {-1e30f, -1e30f, -1e30f, -1e30f}};

    const int NT = SEQ / 64;
    for (int kt = 0; kt < NT; ++kt) {
        __syncthreads();   // prev tile's K reads complete
        #pragma unroll
        for (int c = 0; c < 4; ++c)
            *reinterpret_cast<uint4*>(&k_s[sr * 72 + h4 * 32 + c * 8]) = kr[c];
        __syncthreads();

        // Issue V fragment loads for THIS tile early (global, L1/L2-resident);
        // consumed after softmax -> latency hides under QK^T + softmax.
        bf16x8 vf[4][2];
        #pragma unroll
        for (int jd = 0; jd < 4; ++jd)
            #pragma unroll
            for (int h2 = 0; h2 < 2; ++h2)
                vf[jd][h2] = *reinterpret_cast<const bf16x8*>(
                    &Vtg[vtb + (size_t)(jd * 16 + lr) * SEQ + kt * 64 + h2 * 32 + kg * 8]);

        // Prefetch next K tile into registers
        if (kt + 1 < NT) {
            #pragma unroll
            for (int c = 0; c < 4; ++c)
                kr[c] = *reinterpret_cast<const uint4*>(
                    &Kgl[sbase + (size_t)((kt + 1) * 64 + sr) * HDIM + h4 * 32 + c * 8]);
        }

        // ---- QK^T: S[32 q][64 keys]; K frags shared by both q-streams ----
        f32x4 st[2][4] = {};
        __builtin_amdgcn_s_setprio(1);
        #pragma unroll
        for (int jk = 0; jk < 4; ++jk) {
            const bf16x8 kf0 = *reinterpret_cast<const bf16x8*>(
                &k_s[(jk * 16 + lr) * 72 + kg * 8]);
            const bf16x8 kf1 = *reinterpret_cast<const bf16x8*>(
                &k_s[(jk * 16 + lr) * 72 + 32 + kg * 8]);
            #pragma unroll
            for (int qs = 0; qs < 2; ++qs) {
                st[qs][jk] = __builtin_amdgcn_mfma_f32_16x16x32_bf16(
                    qf[qs][0], kf0, st[qs][jk], 0, 0, 0);
                st[qs][jk] = __builtin_amdgcn_mfma_f32_16x16x32_bf16(
                    qf[qs][1], kf1, st[qs][jk], 0, 0, 0);
            }
        }
        __builtin_amdgcn_s_setprio(0);

        // ---- online softmax (max via shfl; sum via ones-MFMA) ----
        unsigned pk01[2][4], pk23[2][4];
        float f[2][4];
        #pragma unroll
        for (int qs = 0; qs < 2; ++qs) {
            float mx[4];
            #pragma unroll
            for (int q = 0; q < 4; ++q)
                mx[q] = fmaxf(fmaxf(st[qs][0][q], st[qs][1][q]),
                              fmaxf(st[qs][2][q], st[qs][3][q]));
            #pragma unroll
            for (int s = 1; s < 16; s <<= 1)
                #pragma unroll
                for (int q = 0; q < 4; ++q)
                    mx[q] = fmaxf(mx[q], __shfl_xor(mx[q], s));
            #pragma unroll
            for (int q = 0; q < 4; ++q) {
                const float mn = fmaxf(m_run[qs][q], mx[q]);
                f[qs][q] = __expf(m_run[qs][q] - mn);
                m_run[qs][q] = mn;
            }
            #pragma unroll
            for (int jk = 0; jk < 4; ++jk) {
                pk01[qs][jk] = pack_bf16x2(__expf(st[qs][jk][0] - m_run[qs][0]),
                                           __expf(st[qs][jk][1] - m_run[qs][1]));
                pk23[qs][jk] = pack_bf16x2(__expf(st[qs][jk][2] - m_run[qs][2]),
                                           __expf(st[qs][jk][3] - m_run[qs][3]));
            }
            #pragma unroll
            for (int q = 0; q < 4; ++q) l_acc[qs][q] *= f[qs][q];
            #pragma unroll
            for (int jd = 0; jd < 4; ++jd)
                #pragma unroll
                for (int q = 0; q < 4; ++q)
                    oa[qs][jd][q] *= f[qs][q];
        }

        // ---- P -> wave-private LDS -> A-frag layout (no barrier needed) ----
        const int pbase = w * (32 * 72);
        #pragma unroll
        for (int qs = 0; qs < 2; ++qs)
            #pragma unroll
            for (int jk = 0; jk < 4; ++jk) {
                const int rb = pbase + (qs * 16 + kg * 4) * 72 + jk * 16 + lr;
                p_s[rb]           = (unsigned short)(pk01[qs][jk] & 0xFFFFu);
                p_s[rb + 72]      = (unsigned short)(pk01[qs][jk] >> 16);
                p_s[rb + 144]     = (unsigned short)(pk23[qs][jk] & 0xFFFFu);
                p_s[rb + 216]     = (unsigned short)(pk23[qs][jk] >> 16);
            }
        bf16x8 pf[2][2];
        #pragma unroll
        for (int qs = 0; qs < 2; ++qs) {
            pf[qs][0] = *reinterpret_cast<const bf16x8*>(
                &p_s[pbase + (qs * 16 + lr) * 72 + kg * 8]);
            pf[qs][1] = *reinterpret_cast<const bf16x8*>(
                &p_s[pbase + (qs * 16 + lr) * 72 + 32 + kg * 8]);
        }

        // ---- PV + l-sum ----
        __builtin_amdgcn_s_setprio(1);
        #pragma unroll
        for (int qs = 0; qs < 2; ++qs) {
            l_acc[qs] = __builtin_amdgcn_mfma_f32_16x16x32_bf16(
                pf[qs][0], ones, l_acc[qs], 0, 0, 0);
            l_acc[qs] = __builtin_amdgcn_mfma_f32_16x16x32_bf16(
                pf[qs][1], ones, l_acc[qs], 0, 0, 0);
        }
        #pragma unroll
        for (int jd = 0; jd < 4; ++jd)
            #pragma unroll
            for (int qs = 0; qs < 2; ++qs) {
                oa[qs][jd] = __builtin_amdgcn_mfma_f32_16x16x32_bf16(
                    pf[qs][0], vf[jd][0], oa[qs][jd], 0, 0, 0);
                oa[qs][jd] = __builtin_amdgcn_mfma_f32_16x16x32_bf16(
                    pf[qs][1], vf[jd][1], oa[qs][jd], 0, 0, 0);
            }
        __builtin_amdgcn_s_setprio(0);
    }

    // ---- normalize + store context (B, S, H*hd) bf16 ----
    const int b = bh / NHEADS, h = bh % NHEADS;
    #pragma unroll
    for (int qs = 0; qs < 2; ++qs)
        #pragma unroll
        for (int q = 0; q < 4; ++q) {
            const float inv = 1.0f / l_acc[qs][q];
            const int s = q0 + qs * 16 + kg * 4 + q;
            #pragma unroll
            for (int jd = 0; jd < 4; ++jd)
                Cctx[(size_t)(b * SEQ + s) * DMODEL + h * HDIM + jd * 16 + lr] =
                    to_bf16(oa[qs][jd][q] * inv);
        }
}

// ---------------------------------------------------------------------------
extern "C" void kernel_launch(void* const* d_in, const int* in_sizes, int n_in,
                              void* d_out, int out_size, void* d_ws, size_t ws_size,
                              hipStream_t stream) {
    const float* x  = (const float*)d_in[0];
    const float* Wq = (const float*)d_in[1];
    const float* bq = (const float*)d_in[2];
    const float* Wk = (const float*)d_in[3];
    const float* bk = (const float*)d_in[4];
    const float* Wv = (const float*)d_in[5];
    const float* bv = (const float*)d_in[6];
    const float* Wo = (const float*)d_in[7];
    const float* bo = (const float*)d_in[8];
    float* out = (float*)d_out;

    const size_t MD = (size_t)MROWS * DMODEL;    // 3,145,728
    const size_t W2 = (size_t)DMODEL * DMODEL;   // 589,824
    unsigned short* u = (unsigned short*)d_ws;
    unsigned short* x_bf   = u;            // bf16 x (M x 768)
    unsigned short* q_bf   = u + MD;       // bf16 Q (B,H,S,hd), pre-scaled
    unsigned short* k_bf   = u + 2 * MD;   // bf16 K (B,H,S,hd)
    unsigned short* vt_bf  = u + 3 * MD;   // bf16 V^T (B,H,hd,S)
    unsigned short* c_bf   = u + 4 * MD;   // bf16 context (B,S,768)
    unsigned short* wt_all = u + 5 * MD;   // [Wq^T;Wk^T;Wv^T] bf16 (2304 x 768)
    unsigned short* wot    = wt_all + 3 * W2;
    // total: (5*MD + 4*W2)*2B = 36.2 MB

    cvt_all<<<3072 + 4 * 576, 256, 0, stream>>>(x, Wq, Wk, Wv, Wo,
                                                x_bf, wt_all, wot);

    dim3 gq(3 * DMODEL / 128, MROWS / 128);   // (18, 32) = 576 blocks
    gemm_qkv<<<gq, 256, 0, stream>>>(x_bf, wt_all, bq, bk, bv, q_bf, k_bf, vt_bf);

    dim3 ga(SEQ / 64, BATCH * NHEADS);        // (32, 24) = 768 blocks, 3/CU
    flash_mfma<<<ga, 128, 0, stream>>>(q_bf, k_bf, vt_bf, c_bf);

    dim3 gg(DMODEL / 128, MROWS / 128);       // (6, 32)
    gemm_out<<<gg, 256, 0, stream>>>(c_bf, wot, bo, out);
}

// Round 11
// 233.636 us; speedup vs baseline: 1.0819x; 1.0819x over previous
//
#include <hip/hip_runtime.h>
#include <hip/hip_bf16.h>

#define NHEADS 12
#define HDIM 64
#define BATCH 2
#define SEQ 2048
#define DMODEL 768
#define MROWS (BATCH * SEQ)   // 4096

typedef __bf16  bf16x8 __attribute__((ext_vector_type(8)));
typedef float   f32x4  __attribute__((ext_vector_type(4)));

__device__ inline unsigned short to_bf16(float f) {
    union { float f; unsigned u; } x; x.f = f;
    const unsigned r = x.u + 0x7FFFu + ((x.u >> 16) & 1u);   // RNE
    return (unsigned short)(r >> 16);
}
__device__ inline unsigned pack_bf16x2(float a, float b) {
    const __hip_bfloat162 h = __float22bfloat162_rn(float2{a, b});
    union { __hip_bfloat162 h; unsigned u; } c; c.h = h; return c.u;
}

// async global->LDS, 16B per lane, dest = wave-uniform base + lane*16
#define GLDS16(gsrc, ldst)                                                    \
    __builtin_amdgcn_global_load_lds(                                         \
        (const __attribute__((address_space(1))) void*)(gsrc),                \
        (__attribute__((address_space(3))) void*)(ldst), 16, 0, 0)

// ---------------------------------------------------------------------------
// cvt_all: one dispatch for (a) x fp32->bf16 and (b) 4x W transpose+cast.
// ---------------------------------------------------------------------------
__global__ __launch_bounds__(256) void cvt_all(const float* __restrict__ x,
                                               const float* __restrict__ Wq,
                                               const float* __restrict__ Wk,
                                               const float* __restrict__ Wv,
                                               const float* __restrict__ Wo,
                                               unsigned short* __restrict__ x_bf,
                                               unsigned short* __restrict__ wt_all,
                                               unsigned short* __restrict__ wot) {
    __shared__ float tile[32][33];
    const int bid = blockIdx.x;
    if (bid < 3072) {
        const int i = bid * 256 + threadIdx.x;
        const float4 v = reinterpret_cast<const float4*>(x)[i];
        ushort4 o;
        o.x = to_bf16(v.x); o.y = to_bf16(v.y);
        o.z = to_bf16(v.z); o.w = to_bf16(v.w);
        reinterpret_cast<ushort4*>(x_bf)[i] = o;
        return;
    }
    const int wz = bid - 3072;
    const int z = wz / 576, r2 = wz % 576;
    const int bx = r2 % 24, by = r2 / 24;
    const float* W = (z == 0) ? Wq : (z == 1) ? Wk : (z == 2) ? Wv : Wo;
    unsigned short* out = (z < 3) ? (wt_all + (size_t)z * DMODEL * DMODEL) : wot;

    const int tx = threadIdx.x & 31, ty = threadIdx.x >> 5;
    const int nbase = bx * 32, kbase = by * 32;

    #pragma unroll
    for (int p = 0; p < 4; ++p) {
        const int r = ty + p * 8;
        tile[r][tx] = W[(size_t)(kbase + r) * DMODEL + nbase + tx];
    }
    __syncthreads();
    #pragma unroll
    for (int p = 0; p < 4; ++p) {
        const int r = ty + p * 8;
        out[(size_t)(nbase + r) * DMODEL + kbase + tx] = to_bf16(tile[tx][r]);
    }
}

// ---------------------------------------------------------------------------
// Fused QKV GEMM: A (4096 x 768 bf16) @ Wt^T (Wt: 2304 x 768 bf16 [n][k]).
// seg = n/768 selects {Q scatter, K scatter, V^T scatter}. 128x128 tile.
// ---------------------------------------------------------------------------
__global__ __launch_bounds__(256) void gemm_qkv(const unsigned short* __restrict__ A,
                                                const unsigned short* __restrict__ Wt,
                                                const float* __restrict__ bq,
                                                const float* __restrict__ bk,
                                                const float* __restrict__ bv,
                                                unsigned short* __restrict__ q_bf,
                                                unsigned short* __restrict__ k_bf,
                                                unsigned short* __restrict__ vt_bf) {
    constexpr int K = DMODEL;
    __shared__ unsigned short As[128 * 32];
    __shared__ unsigned short Bs[128 * 32];

    const int t = threadIdx.x;
    const int lane = t & 63;
    const int w = t >> 6, wr = w >> 1, wc = w & 1;
    const int m0 = blockIdx.y * 128, n0 = blockIdx.x * 128;
    const int lr = lane & 15;
    const int kg = lane >> 4;

    const int row0 = t >> 2,        cp0 = t & 3;
    const int row1 = (t + 256) >> 2, cp1 = t & 3;
    const int c0 = cp0 ^ ((row0 >> 1) & 3);
    const int c1 = cp1 ^ ((row1 >> 1) & 3);
    unsigned short* asd0 = &As[(w * 64) * 8];
    unsigned short* asd1 = &As[(256 + w * 64) * 8];
    unsigned short* bsd0 = &Bs[(w * 64) * 8];
    unsigned short* bsd1 = &Bs[(256 + w * 64) * 8];

    f32x4 acc[4][4] = {};

    for (int k0 = 0; k0 < K; k0 += 32) {
        GLDS16(A  + (size_t)(m0 + row0) * K + k0 + c0 * 8, asd0);
        GLDS16(A  + (size_t)(m0 + row1) * K + k0 + c1 * 8, asd1);
        GLDS16(Wt + (size_t)(n0 + row0) * K + k0 + c0 * 8, bsd0);
        GLDS16(Wt + (size_t)(n0 + row1) * K + k0 + c1 * 8, bsd1);
        __syncthreads();

        bf16x8 af[4], bfr[4];
        #pragma unroll
        for (int i = 0; i < 4; ++i) {
            const int ar = wr * 64 + i * 16 + lr;
            af[i] = *reinterpret_cast<const bf16x8*>(
                &As[ar * 32 + ((kg ^ ((ar >> 1) & 3)) * 8)]);
            const int br = wc * 64 + i * 16 + lr;
            bfr[i] = *reinterpret_cast<const bf16x8*>(
                &Bs[br * 32 + ((kg ^ ((br >> 1) & 3)) * 8)]);
        }
        #pragma unroll
        for (int i = 0; i < 4; ++i)
            #pragma unroll
            for (int j = 0; j < 4; ++j)
                acc[i][j] = __builtin_amdgcn_mfma_f32_16x16x32_bf16(
                    af[i], bfr[j], acc[i][j], 0, 0, 0);
        __syncthreads();
    }

    const int seg = n0 / DMODEL;
    const float scale = (seg == 0) ? 0.125f : 1.0f;
    const float* bias = (seg == 0) ? bq : (seg == 1) ? bk : bv;
    const int mb = m0 + wr * 64, nb = n0 - seg * DMODEL + wc * 64;

    #pragma unroll
    for (int i = 0; i < 4; ++i) {
        #pragma unroll
        for (int j = 0; j < 4; ++j) {
            const int cl = nb + j * 16 + lr;
            const float bv_ = bias[cl];
            const int h = cl >> 6, d = cl & (HDIM - 1);
            if (seg < 2) {
                unsigned short* dst = (seg == 0) ? q_bf : k_bf;
                #pragma unroll
                for (int q = 0; q < 4; ++q) {
                    const int row = mb + i * 16 + kg * 4 + q;
                    const int b = row >> 11, s = row & (SEQ - 1);
                    dst[(((size_t)(b * NHEADS + h)) * SEQ + s) * HDIM + d] =
                        to_bf16((acc[i][j][q] + bv_) * scale);
                }
            } else {
                ushort4 pk;
                #pragma unroll
                for (int q = 0; q < 4; ++q)
                    ((unsigned short*)&pk)[q] = to_bf16(acc[i][j][q] + bv_);
                const int r0 = mb + i * 16 + kg * 4;
                const int b = r0 >> 11, s = r0 & (SEQ - 1);
                *reinterpret_cast<ushort4*>(
                    &vt_bf[(((size_t)(b * NHEADS + h)) * HDIM + d) * SEQ + s]) = pk;
            }
        }
    }
}

// ---------------------------------------------------------------------------
// Out-projection GEMM, 64x64 tiles: C = A (4096 x 768 bf16) @ Wo^T + bo.
// grid (12, 64) = 768 blocks -> 3 blocks/CU (was 192 = 0.75/CU at 128x128).
// 4 waves (2x2), each wave 32x32 via 2x2 frags.
// ---------------------------------------------------------------------------
__global__ __launch_bounds__(256) void gemm_out(const unsigned short* __restrict__ A,
                                                const unsigned short* __restrict__ Bt,
                                                const float* __restrict__ bias,
                                                float* __restrict__ out) {
    constexpr int K = DMODEL;
    __shared__ unsigned short As[64 * 32];   // 4 KB
    __shared__ unsigned short Bs[64 * 32];

    const int t = threadIdx.x;
    const int lane = t & 63;
    const int w = t >> 6, wr = w >> 1, wc = w & 1;
    const int m0 = blockIdx.y * 64, n0 = blockIdx.x * 64;
    const int lr = lane & 15;
    const int kg = lane >> 4;

    // staging: 256 chunks of 16B per tile, one per thread
    const int row = t >> 2, cp = t & 3;
    const int c = cp ^ ((row >> 1) & 3);
    unsigned short* asd = &As[(w * 16) * 32];
    unsigned short* bsd = &Bs[(w * 16) * 32];

    f32x4 acc[2][2] = {};

    for (int k0 = 0; k0 < K; k0 += 32) {
        GLDS16(A  + (size_t)(m0 + row) * K + k0 + c * 8, asd);
        GLDS16(Bt + (size_t)(n0 + row) * K + k0 + c * 8, bsd);
        __syncthreads();

        bf16x8 af[2], bfr[2];
        #pragma unroll
        for (int i = 0; i < 2; ++i) {
            const int ar = wr * 32 + i * 16 + lr;
            af[i] = *reinterpret_cast<const bf16x8*>(
                &As[ar * 32 + ((kg ^ ((ar >> 1) & 3)) * 8)]);
            const int br = wc * 32 + i * 16 + lr;
            bfr[i] = *reinterpret_cast<const bf16x8*>(
                &Bs[br * 32 + ((kg ^ ((br >> 1) & 3)) * 8)]);
        }
        #pragma unroll
        for (int i = 0; i < 2; ++i)
            #pragma unroll
            for (int j = 0; j < 2; ++j)
                acc[i][j] = __builtin_amdgcn_mfma_f32_16x16x32_bf16(
                    af[i], bfr[j], acc[i][j], 0, 0, 0);
        __syncthreads();
    }

    const int mb = m0 + wr * 32, nb = n0 + wc * 32;
    #pragma unroll
    for (int i = 0; i < 2; ++i) {
        #pragma unroll
        for (int j = 0; j < 2; ++j) {
            const int col = nb + j * 16 + lr;
            const float bv = bias[col];
            #pragma unroll
            for (int q = 0; q < 4; ++q) {
                const int row2 = mb + i * 16 + kg * 4 + q;
                out[(size_t)row2 * DMODEL + col] = acc[i][j][q] + bv;
            }
        }
    }
}

// ---------------------------------------------------------------------------
// MFMA flash attention v3 = Round-6 occupancy + v2's V-from-global.
// Grid (SEQ/64, B*H), 256 threads = 4 waves, each wave 16 q-rows.
// K reg-staged into padded LDS (9.2 KB); V^T fragments DIRECT from global
// (proven correct+traffic-absorbed in v2); P via per-wave LDS; l via
// ones-MFMA. 12 waves/CU restored (v2's 6 waves/CU was the regression).
// ---------------------------------------------------------------------------
__global__ __launch_bounds__(256, 3) void flash_mfma(
        const unsigned short* __restrict__ Qg,
        const unsigned short* __restrict__ Kgl,
        const unsigned short* __restrict__ Vtg,
        unsigned short* __restrict__ Cctx) {
    __shared__ __align__(16) unsigned short k_s[64 * 72];
    __shared__ __align__(16) unsigned short p_s[4 * 16 * 72];

    const int t = threadIdx.x;
    const int lane = t & 63, w = t >> 6;          // w in 0..3
    const int lr = lane & 15, kg = lane >> 4;
    const int qb = blockIdx.x, bh = blockIdx.y;
    const size_t sbase = (size_t)bh * SEQ * HDIM;   // Q/K: (B,H,S,hd)
    const size_t vtb   = (size_t)bh * HDIM * SEQ;   // Vt:  (B,H,hd,S)

    const int q0 = qb * 64 + w * 16;
    const bf16x8 qf0 = *reinterpret_cast<const bf16x8*>(
        &Qg[sbase + (size_t)(q0 + lr) * HDIM + kg * 8]);
    const bf16x8 qf1 = *reinterpret_cast<const bf16x8*>(
        &Qg[sbase + (size_t)(q0 + lr) * HDIM + 32 + kg * 8]);

    bf16x8 ones;
    #pragma unroll
    for (int i = 0; i < 8; ++i) ones[i] = (__bf16)1.0f;

    // K staging: thread covers row sr, 16B chunks {cst, cst+4}
    const int sr = t >> 2, cst = t & 3;

    uint4 kr0, kr1;
    {
        const size_t ka = sbase + (size_t)sr * HDIM;
        kr0 = *reinterpret_cast<const uint4*>(&Kgl[ka + cst * 8]);
        kr1 = *reinterpret_cast<const uint4*>(&Kgl[ka + (cst + 4) * 8]);
    }

    f32x4 oa[4] = {};
    f32x4 l_acc = {};
    float m_run[4] = {-1e30f, -1e30f, -1e30f, -1e30f};

    const int NT = SEQ / 64;
    for (int kt = 0; kt < NT; ++kt) {
        __syncthreads();   // prev tile's K reads complete
        *reinterpret_cast<uint4*>(&k_s[sr * 72 + cst * 8])       = kr0;
        *reinterpret_cast<uint4*>(&k_s[sr * 72 + (cst + 4) * 8]) = kr1;
        __syncthreads();

        // V fragments for THIS tile from global (issued early; consumed
        // after softmax -> ~500cy latency hides under QK^T + softmax).
        bf16x8 vf[4][2];
        #pragma unroll
        for (int jd = 0; jd < 4; ++jd)
            #pragma unroll
            for (int h2 = 0; h2 < 2; ++h2)
                vf[jd][h2] = *reinterpret_cast<const bf16x8*>(
                    &Vtg[vtb + (size_t)(jd * 16 + lr) * SEQ + kt * 64 + h2 * 32 + kg * 8]);

        // Prefetch next K tile into registers
        if (kt + 1 < NT) {
            const size_t ka = sbase + (size_t)((kt + 1) * 64 + sr) * HDIM;
            kr0 = *reinterpret_cast<const uint4*>(&Kgl[ka + cst * 8]);
            kr1 = *reinterpret_cast<const uint4*>(&Kgl[ka + (cst + 4) * 8]);
        }

        // ---- QK^T: S[16 q][64 keys] ----
        f32x4 st[4] = {};
        __builtin_amdgcn_s_setprio(1);
        #pragma unroll
        for (int jk = 0; jk < 4; ++jk) {
            const bf16x8 kf0 = *reinterpret_cast<const bf16x8*>(
                &k_s[(jk * 16 + lr) * 72 + kg * 8]);
            const bf16x8 kf1 = *reinterpret_cast<const bf16x8*>(
                &k_s[(jk * 16 + lr) * 72 + 32 + kg * 8]);
            st[jk] = __builtin_amdgcn_mfma_f32_16x16x32_bf16(qf0, kf0, st[jk], 0, 0, 0);
            st[jk] = __builtin_amdgcn_mfma_f32_16x16x32_bf16(qf1, kf1, st[jk], 0, 0, 0);
        }
        __builtin_amdgcn_s_setprio(0);

        // ---- online softmax (max via shfl; sum via ones-MFMA) ----
        float mx[4];
        #pragma unroll
        for (int q = 0; q < 4; ++q)
            mx[q] = fmaxf(fmaxf(st[0][q], st[1][q]), fmaxf(st[2][q], st[3][q]));
        #pragma unroll
        for (int s = 1; s < 16; s <<= 1)
            #pragma unroll
            for (int q = 0; q < 4; ++q)
                mx[q] = fmaxf(mx[q], __shfl_xor(mx[q], s));

        float f[4];
        #pragma unroll
        for (int q = 0; q < 4; ++q) {
            const float mn = fmaxf(m_run[q], mx[q]);
            f[q] = __expf(m_run[q] - mn);
            m_run[q] = mn;
        }

        unsigned pk01[4], pk23[4];
        #pragma unroll
        for (int jk = 0; jk < 4; ++jk) {
            pk01[jk] = pack_bf16x2(__expf(st[jk][0] - m_run[0]),
                                   __expf(st[jk][1] - m_run[1]));
            pk23[jk] = pack_bf16x2(__expf(st[jk][2] - m_run[2]),
                                   __expf(st[jk][3] - m_run[3]));
        }

        #pragma unroll
        for (int q = 0; q < 4; ++q) l_acc[q] *= f[q];
        #pragma unroll
        for (int jd = 0; jd < 4; ++jd)
            #pragma unroll
            for (int q = 0; q < 4; ++q)
                oa[jd][q] *= f[q];

        // ---- P -> per-wave LDS -> A-frag layout (wave-private) ----
        const int pbase = w * (16 * 72);
        #pragma unroll
        for (int jk = 0; jk < 4; ++jk) {
            p_s[pbase + (kg * 4 + 0) * 72 + jk * 16 + lr] = (unsigned short)(pk01[jk] & 0xFFFFu);
            p_s[pbase + (kg * 4 + 1) * 72 + jk * 16 + lr] = (unsigned short)(pk01[jk] >> 16);
            p_s[pbase + (kg * 4 + 2) * 72 + jk * 16 + lr] = (unsigned short)(pk23[jk] & 0xFFFFu);
            p_s[pbase + (kg * 4 + 3) * 72 + jk * 16 + lr] = (unsigned short)(pk23[jk] >> 16);
        }
        const bf16x8 pf0 = *reinterpret_cast<const bf16x8*>(
            &p_s[pbase + lr * 72 + kg * 8]);
        const bf16x8 pf1 = *reinterpret_cast<const bf16x8*>(
            &p_s[pbase + lr * 72 + 32 + kg * 8]);

        // ---- PV + l-sum ----
        __builtin_amdgcn_s_setprio(1);
        l_acc = __builtin_amdgcn_mfma_f32_16x16x32_bf16(pf0, ones, l_acc, 0, 0, 0);
        l_acc = __builtin_amdgcn_mfma_f32_16x16x32_bf16(pf1, ones, l_acc, 0, 0, 0);
        #pragma unroll
        for (int jd = 0; jd < 4; ++jd) {
            oa[jd] = __builtin_amdgcn_mfma_f32_16x16x32_bf16(pf0, vf[jd][0], oa[jd], 0, 0, 0);
            oa[jd] = __builtin_amdgcn_mfma_f32_16x16x32_bf16(pf1, vf[jd][1], oa[jd], 0, 0, 0);
        }
        __builtin_amdgcn_s_setprio(0);
    }

    // ---- normalize + store context (B, S, H*hd) bf16 ----
    const int b = bh / NHEADS, h = bh % NHEADS;
    #pragma unroll
    for (int q = 0; q < 4; ++q) {
        const float inv = 1.0f / l_acc[q];
        const int s = q0 + kg * 4 + q;
        #pragma unroll
        for (int jd = 0; jd < 4; ++jd)
            Cctx[(size_t)(b * SEQ + s) * DMODEL + h * HDIM + jd * 16 + lr] =
                to_bf16(oa[jd][q] * inv);
    }
}

// ---------------------------------------------------------------------------
extern "C" void kernel_launch(void* const* d_in, const int* in_sizes, int n_in,
                              void* d_out, int out_size, void* d_ws, size_t ws_size,
                              hipStream_t stream) {
    const float* x  = (const float*)d_in[0];
    const float* Wq = (const float*)d_in[1];
    const float* bq = (const float*)d_in[2];
    const float* Wk = (const float*)d_in[3];
    const float* bk = (const float*)d_in[4];
    const float* Wv = (const float*)d_in[5];
    const float* bv = (const float*)d_in[6];
    const float* Wo = (const float*)d_in[7];
    const float* bo = (const float*)d_in[8];
    float* out = (float*)d_out;

    const size_t MD = (size_t)MROWS * DMODEL;    // 3,145,728
    const size_t W2 = (size_t)DMODEL * DMODEL;   // 589,824
    unsigned short* u = (unsigned short*)d_ws;
    unsigned short* x_bf   = u;            // bf16 x (M x 768)
    unsigned short* q_bf   = u + MD;       // bf16 Q (B,H,S,hd), pre-scaled
    unsigned short* k_bf   = u + 2 * MD;   // bf16 K (B,H,S,hd)
    unsigned short* vt_bf  = u + 3 * MD;   // bf16 V^T (B,H,hd,S)
    unsigned short* c_bf   = u + 4 * MD;   // bf16 context (B,S,768)
    unsigned short* wt_all = u + 5 * MD;   // [Wq^T;Wk^T;Wv^T] bf16 (2304 x 768)
    unsigned short* wot    = wt_all + 3 * W2;
    // total: (5*MD + 4*W2)*2B = 36.2 MB

    cvt_all<<<3072 + 4 * 576, 256, 0, stream>>>(x, Wq, Wk, Wv, Wo,
                                                x_bf, wt_all, wot);

    dim3 gq(3 * DMODEL / 128, MROWS / 128);   // (18, 32) = 576 blocks
    gemm_qkv<<<gq, 256, 0, stream>>>(x_bf, wt_all, bq, bk, bv, q_bf, k_bf, vt_bf);

    dim3 ga(SEQ / 64, BATCH * NHEADS);        // (32, 24) = 768 blocks, 3/CU
    flash_mfma<<<ga, 256, 0, stream>>>(q_bf, k_bf, vt_bf, c_bf);

    dim3 go(DMODEL / 64, MROWS / 64);         // (12, 64) = 768 blocks, 3/CU
    gemm_out<<<go, 256, 0, stream>>>(c_bf, wot, bo, out);
}

// Round 13
// 208.455 us; speedup vs baseline: 1.2126x; 1.1208x over previous
//
#include <hip/hip_runtime.h>
#include <hip/hip_bf16.h>

#define NHEADS 12
#define HDIM 64
#define BATCH 2
#define SEQ 2048
#define DMODEL 768
#define MROWS (BATCH * SEQ)   // 4096

typedef __bf16  bf16x8 __attribute__((ext_vector_type(8)));
typedef float   f32x4  __attribute__((ext_vector_type(4)));

__device__ inline unsigned short to_bf16(float f) {
    union { float f; unsigned u; } x; x.f = f;
    const unsigned r = x.u + 0x7FFFu + ((x.u >> 16) & 1u);   // RNE
    return (unsigned short)(r >> 16);
}
__device__ inline unsigned pack_bf16x2(float a, float b) {
    const __hip_bfloat162 h = __float22bfloat162_rn(float2{a, b});
    union { __hip_bfloat162 h; unsigned u; } c; c.h = h; return c.u;
}

// async global->LDS, 16B per lane, dest = wave-uniform base + lane*16
#define GLDS16(gsrc, ldst)                                                    \
    __builtin_amdgcn_global_load_lds(                                         \
        (const __attribute__((address_space(1))) void*)(gsrc),                \
        (__attribute__((address_space(3))) void*)(ldst), 16, 0, 0)

// ---------------------------------------------------------------------------
// cvt_all: one dispatch for (a) x fp32->bf16 and (b) 4x W transpose+cast.
// ---------------------------------------------------------------------------
__global__ __launch_bounds__(256) void cvt_all(const float* __restrict__ x,
                                               const float* __restrict__ Wq,
                                               const float* __restrict__ Wk,
                                               const float* __restrict__ Wv,
                                               const float* __restrict__ Wo,
                                               unsigned short* __restrict__ x_bf,
                                               unsigned short* __restrict__ wt_all,
                                               unsigned short* __restrict__ wot) {
    __shared__ float tile[32][33];
    const int bid = blockIdx.x;
    if (bid < 3072) {
        const int i = bid * 256 + threadIdx.x;
        const float4 v = reinterpret_cast<const float4*>(x)[i];
        ushort4 o;
        o.x = to_bf16(v.x); o.y = to_bf16(v.y);
        o.z = to_bf16(v.z); o.w = to_bf16(v.w);
        reinterpret_cast<ushort4*>(x_bf)[i] = o;
        return;
    }
    const int wz = bid - 3072;
    const int z = wz / 576, r2 = wz % 576;
    const int bx = r2 % 24, by = r2 / 24;
    const float* W = (z == 0) ? Wq : (z == 1) ? Wk : (z == 2) ? Wv : Wo;
    unsigned short* out = (z < 3) ? (wt_all + (size_t)z * DMODEL * DMODEL) : wot;

    const int tx = threadIdx.x & 31, ty = threadIdx.x >> 5;
    const int nbase = bx * 32, kbase = by * 32;

    #pragma unroll
    for (int p = 0; p < 4; ++p) {
        const int r = ty + p * 8;
        tile[r][tx] = W[(size_t)(kbase + r) * DMODEL + nbase + tx];
    }
    __syncthreads();
    #pragma unroll
    for (int p = 0; p < 4; ++p) {
        const int r = ty + p * 8;
        out[(size_t)(nbase + r) * DMODEL + kbase + tx] = to_bf16(tile[tx][r]);
    }
}

// ---------------------------------------------------------------------------
// Fused QKV GEMM: A (4096 x 768 bf16) @ Wt^T (Wt: 2304 x 768 bf16 [n][k]).
// seg = n/768 selects {Q scatter, K scatter, V^T scatter}. 128x128 tile.
// ---------------------------------------------------------------------------
__global__ __launch_bounds__(256) void gemm_qkv(const unsigned short* __restrict__ A,
                                                const unsigned short* __restrict__ Wt,
                                                const float* __restrict__ bq,
                                                const float* __restrict__ bk,
                                                const float* __restrict__ bv,
                                                unsigned short* __restrict__ q_bf,
                                                unsigned short* __restrict__ k_bf,
                                                unsigned short* __restrict__ vt_bf) {
    constexpr int K = DMODEL;
    __shared__ unsigned short As[128 * 32];
    __shared__ unsigned short Bs[128 * 32];

    const int t = threadIdx.x;
    const int lane = t & 63;
    const int w = t >> 6, wr = w >> 1, wc = w & 1;
    const int m0 = blockIdx.y * 128, n0 = blockIdx.x * 128;
    const int lr = lane & 15;
    const int kg = lane >> 4;

    const int row0 = t >> 2,        cp0 = t & 3;
    const int row1 = (t + 256) >> 2, cp1 = t & 3;
    const int c0 = cp0 ^ ((row0 >> 1) & 3);
    const int c1 = cp1 ^ ((row1 >> 1) & 3);
    unsigned short* asd0 = &As[(w * 64) * 8];
    unsigned short* asd1 = &As[(256 + w * 64) * 8];
    unsigned short* bsd0 = &Bs[(w * 64) * 8];
    unsigned short* bsd1 = &Bs[(256 + w * 64) * 8];

    f32x4 acc[4][4] = {};

    for (int k0 = 0; k0 < K; k0 += 32) {
        GLDS16(A  + (size_t)(m0 + row0) * K + k0 + c0 * 8, asd0);
        GLDS16(A  + (size_t)(m0 + row1) * K + k0 + c1 * 8, asd1);
        GLDS16(Wt + (size_t)(n0 + row0) * K + k0 + c0 * 8, bsd0);
        GLDS16(Wt + (size_t)(n0 + row1) * K + k0 + c1 * 8, bsd1);
        __syncthreads();

        bf16x8 af[4], bfr[4];
        #pragma unroll
        for (int i = 0; i < 4; ++i) {
            const int ar = wr * 64 + i * 16 + lr;
            af[i] = *reinterpret_cast<const bf16x8*>(
                &As[ar * 32 + ((kg ^ ((ar >> 1) & 3)) * 8)]);
            const int br = wc * 64 + i * 16 + lr;
            bfr[i] = *reinterpret_cast<const bf16x8*>(
                &Bs[br * 32 + ((kg ^ ((br >> 1) & 3)) * 8)]);
        }
        #pragma unroll
        for (int i = 0; i < 4; ++i)
            #pragma unroll
            for (int j = 0; j < 4; ++j)
                acc[i][j] = __builtin_amdgcn_mfma_f32_16x16x32_bf16(
                    af[i], bfr[j], acc[i][j], 0, 0, 0);
        __syncthreads();
    }

    const int seg = n0 / DMODEL;
    const float scale = (seg == 0) ? 0.125f : 1.0f;
    const float* bias = (seg == 0) ? bq : (seg == 1) ? bk : bv;
    const int mb = m0 + wr * 64, nb = n0 - seg * DMODEL + wc * 64;

    #pragma unroll
    for (int i = 0; i < 4; ++i) {
        #pragma unroll
        for (int j = 0; j < 4; ++j) {
            const int cl = nb + j * 16 + lr;
            const float bv_ = bias[cl];
            const int h = cl >> 6, d = cl & (HDIM - 1);
            if (seg < 2) {
                unsigned short* dst = (seg == 0) ? q_bf : k_bf;
                #pragma unroll
                for (int q = 0; q < 4; ++q) {
                    const int row = mb + i * 16 + kg * 4 + q;
                    const int b = row >> 11, s = row & (SEQ - 1);
                    dst[(((size_t)(b * NHEADS + h)) * SEQ + s) * HDIM + d] =
                        to_bf16((acc[i][j][q] + bv_) * scale);
                }
            } else {
                ushort4 pk;
                #pragma unroll
                for (int q = 0; q < 4; ++q)
                    ((unsigned short*)&pk)[q] = to_bf16(acc[i][j][q] + bv_);
                const int r0 = mb + i * 16 + kg * 4;
                const int b = r0 >> 11, s = r0 & (SEQ - 1);
                *reinterpret_cast<ushort4*>(
                    &vt_bf[(((size_t)(b * NHEADS + h)) * HDIM + d) * SEQ + s]) = pk;
            }
        }
    }
}

// ---------------------------------------------------------------------------
// Out-projection GEMM, 64x64 tiles: grid (12,64) = 768 blocks -> 3/CU.
// ---------------------------------------------------------------------------
__global__ __launch_bounds__(256) void gemm_out(const unsigned short* __restrict__ A,
                                                const unsigned short* __restrict__ Bt,
                                                const float* __restrict__ bias,
                                                float* __restrict__ out) {
    constexpr int K = DMODEL;
    __shared__ unsigned short As[64 * 32];   // 4 KB
    __shared__ unsigned short Bs[64 * 32];

    const int t = threadIdx.x;
    const int lane = t & 63;
    const int w = t >> 6, wr = w >> 1, wc = w & 1;
    const int m0 = blockIdx.y * 64, n0 = blockIdx.x * 64;
    const int lr = lane & 15;
    const int kg = lane >> 4;

    const int row = t >> 2, cp = t & 3;
    const int c = cp ^ ((row >> 1) & 3);
    unsigned short* asd = &As[(w * 16) * 32];
    unsigned short* bsd = &Bs[(w * 16) * 32];

    f32x4 acc[2][2] = {};

    for (int k0 = 0; k0 < K; k0 += 32) {
        GLDS16(A  + (size_t)(m0 + row) * K + k0 + c * 8, asd);
        GLDS16(Bt + (size_t)(n0 + row) * K + k0 + c * 8, bsd);
        __syncthreads();

        bf16x8 af[2], bfr[2];
        #pragma unroll
        for (int i = 0; i < 2; ++i) {
            const int ar = wr * 32 + i * 16 + lr;
            af[i] = *reinterpret_cast<const bf16x8*>(
                &As[ar * 32 + ((kg ^ ((ar >> 1) & 3)) * 8)]);
            const int br = wc * 32 + i * 16 + lr;
            bfr[i] = *reinterpret_cast<const bf16x8*>(
                &Bs[br * 32 + ((kg ^ ((br >> 1) & 3)) * 8)]);
        }
        #pragma unroll
        for (int i = 0; i < 2; ++i)
            #pragma unroll
            for (int j = 0; j < 2; ++j)
                acc[i][j] = __builtin_amdgcn_mfma_f32_16x16x32_bf16(
                    af[i], bfr[j], acc[i][j], 0, 0, 0);
        __syncthreads();
    }

    const int mb = m0 + wr * 32, nb = n0 + wc * 32;
    #pragma unroll
    for (int i = 0; i < 2; ++i) {
        #pragma unroll
        for (int j = 0; j < 2; ++j) {
            const int col = nb + j * 16 + lr;
            const float bv = bias[col];
            #pragma unroll
            for (int q = 0; q < 4; ++q) {
                const int row2 = mb + i * 16 + kg * 4 + q;
                out[(size_t)row2 * DMODEL + col] = acc[i][j][q] + bv;
            }
        }
    }
}

// ---------------------------------------------------------------------------
// MFMA flash attention v4 = Round-6 verified structure (81 us: K AND V
// reg-staged into padded LDS, 4 waves x 16 q-rows, ones-MFMA l, cvt_pk P)
// + XCD-aware chunked block swizzle (768 blocks % 8 == 0 -> bijective):
// each XCD gets 3 whole heads -> K/V stays in its private L2 (1.5 MB < 4 MB).
// 1D grid 768; decode sw = (bid&7)*96 + bid>>3; bh = sw/32; qb = sw%32.
// ---------------------------------------------------------------------------
__global__ __launch_bounds__(256, 3) void flash_mfma(
        const unsigned short* __restrict__ Qg,
        const unsigned short* __restrict__ Kgl,
        const unsigned short* __restrict__ Vtg,
        unsigned short* __restrict__ Cctx) {
    __shared__ __align__(16) unsigned short k_s[64 * 72];
    __shared__ __align__(16) unsigned short v_s[64 * 72];   // Vt tile: [d][key]
    __shared__ __align__(16) unsigned short p_s[4 * 16 * 72];

    const int t = threadIdx.x;
    const int lane = t & 63, w = t >> 6;
    const int lr = lane & 15, kg = lane >> 4;
    const int bid = blockIdx.x;
    const int sw = (bid & 7) * 96 + (bid >> 3);   // XCD-chunked remap
    const int bh = sw / 32, qb = sw % 32;
    const size_t sbase = (size_t)bh * SEQ * HDIM;   // Q/K: (B,H,S,hd)
    const size_t vtb   = (size_t)bh * HDIM * SEQ;   // Vt:  (B,H,hd,S)

    const int q0 = qb * 64 + w * 16;
    const bf16x8 qf0 = *reinterpret_cast<const bf16x8*>(
        &Qg[sbase + (size_t)(q0 + lr) * HDIM + kg * 8]);
    const bf16x8 qf1 = *reinterpret_cast<const bf16x8*>(
        &Qg[sbase + (size_t)(q0 + lr) * HDIM + 32 + kg * 8]);

    bf16x8 ones;
    #pragma unroll
    for (int i = 0; i < 8; ++i) ones[i] = (__bf16)1.0f;

    // staging: thread covers row sr, 16B chunks {cst, cst+4} of K and Vt
    const int sr = t >> 2, cst = t & 3;

    uint4 kr0, kr1, vr0, vr1;
    {
        const size_t ka = sbase + (size_t)sr * HDIM;
        kr0 = *reinterpret_cast<const uint4*>(&Kgl[ka + cst * 8]);
        kr1 = *reinterpret_cast<const uint4*>(&Kgl[ka + (cst + 4) * 8]);
        const size_t va = vtb + (size_t)sr * SEQ;
        vr0 = *reinterpret_cast<const uint4*>(&Vtg[va + cst * 8]);
        vr1 = *reinterpret_cast<const uint4*>(&Vtg[va + (cst + 4) * 8]);
    }

    f32x4 oa[4] = {};
    f32x4 l_acc = {};
    float m_run[4] = {-1e30f, -1e30f, -1e30f, -1e30f};

    const int NT = SEQ / 64;
    for (int kt = 0; kt < NT; ++kt) {
        __syncthreads();
        *reinterpret_cast<uint4*>(&k_s[sr * 72 + cst * 8])       = kr0;
        *reinterpret_cast<uint4*>(&k_s[sr * 72 + (cst + 4) * 8]) = kr1;
        *reinterpret_cast<uint4*>(&v_s[sr * 72 + cst * 8])       = vr0;
        *reinterpret_cast<uint4*>(&v_s[sr * 72 + (cst + 4) * 8]) = vr1;
        __syncthreads();
        if (kt + 1 < NT) {   // next-tile loads: latency hides under compute
            const size_t ka = sbase + (size_t)((kt + 1) * 64 + sr) * HDIM;
            kr0 = *reinterpret_cast<const uint4*>(&Kgl[ka + cst * 8]);
            kr1 = *reinterpret_cast<const uint4*>(&Kgl[ka + (cst + 4) * 8]);
            const size_t va = vtb + (size_t)sr * SEQ + (kt + 1) * 64;
            vr0 = *reinterpret_cast<const uint4*>(&Vtg[va + cst * 8]);
            vr1 = *reinterpret_cast<const uint4*>(&Vtg[va + (cst + 4) * 8]);
        }

        // ---- QK^T: S[16 q][64 keys] ----
        f32x4 st[4] = {};
        __builtin_amdgcn_s_setprio(1);
        #pragma unroll
        for (int jk = 0; jk < 4; ++jk) {
            const bf16x8 kf0 = *reinterpret_cast<const bf16x8*>(
                &k_s[(jk * 16 + lr) * 72 + kg * 8]);
            const bf16x8 kf1 = *reinterpret_cast<const bf16x8*>(
                &k_s[(jk * 16 + lr) * 72 + 32 + kg * 8]);
            st[jk] = __builtin_amdgcn_mfma_f32_16x16x32_bf16(qf0, kf0, st[jk], 0, 0, 0);
            st[jk] = __builtin_amdgcn_mfma_f32_16x16x32_bf16(qf1, kf1, st[jk], 0, 0, 0);
        }
        __builtin_amdgcn_s_setprio(0);

        // ---- online softmax (max via shfl; sum via ones-MFMA) ----
        float mx[4];
        #pragma unroll
        for (int q = 0; q < 4; ++q)
            mx[q] = fmaxf(fmaxf(st[0][q], st[1][q]), fmaxf(st[2][q], st[3][q]));
        #pragma unroll
        for (int s = 1; s < 16; s <<= 1)
            #pragma unroll
            for (int q = 0; q < 4; ++q)
                mx[q] = fmaxf(mx[q], __shfl_xor(mx[q], s));

        float f[4];
        #pragma unroll
        for (int q = 0; q < 4; ++q) {
            const float mn = fmaxf(m_run[q], mx[q]);
            f[q] = __expf(m_run[q] - mn);
            m_run[q] = mn;
        }

        unsigned pk01[4], pk23[4];
        #pragma unroll
        for (int jk = 0; jk < 4; ++jk) {
            pk01[jk] = pack_bf16x2(__expf(st[jk][0] - m_run[0]),
                                   __expf(st[jk][1] - m_run[1]));
            pk23[jk] = pack_bf16x2(__expf(st[jk][2] - m_run[2]),
                                   __expf(st[jk][3] - m_run[3]));
        }

        #pragma unroll
        for (int q = 0; q < 4; ++q) l_acc[q] *= f[q];
        #pragma unroll
        for (int jd = 0; jd < 4; ++jd)
            #pragma unroll
            for (int q = 0; q < 4; ++q)
                oa[jd][q] *= f[q];

        // ---- P -> per-wave LDS -> A-frag layout ----
        const int pbase = w * (16 * 72);
        #pragma unroll
        for (int jk = 0; jk < 4; ++jk) {
            p_s[pbase + (kg * 4 + 0) * 72 + jk * 16 + lr] = (unsigned short)(pk01[jk] & 0xFFFFu);
            p_s[pbase + (kg * 4 + 1) * 72 + jk * 16 + lr] = (unsigned short)(pk01[jk] >> 16);
            p_s[pbase + (kg * 4 + 2) * 72 + jk * 16 + lr] = (unsigned short)(pk23[jk] & 0xFFFFu);
            p_s[pbase + (kg * 4 + 3) * 72 + jk * 16 + lr] = (unsigned short)(pk23[jk] >> 16);
        }
        const bf16x8 pf0 = *reinterpret_cast<const bf16x8*>(
            &p_s[pbase + lr * 72 + kg * 8]);
        const bf16x8 pf1 = *reinterpret_cast<const bf16x8*>(
            &p_s[pbase + lr * 72 + 32 + kg * 8]);

        // ---- PV + l-sum ----
        __builtin_amdgcn_s_setprio(1);
        l_acc = __builtin_amdgcn_mfma_f32_16x16x32_bf16(pf0, ones, l_acc, 0, 0, 0);
        l_acc = __builtin_amdgcn_mfma_f32_16x16x32_bf16(pf1, ones, l_acc, 0, 0, 0);
        #pragma unroll
        for (int jd = 0; jd < 4; ++jd) {
            const bf16x8 vf0 = *reinterpret_cast<const bf16x8*>(
                &v_s[(jd * 16 + lr) * 72 + kg * 8]);
            const bf16x8 vf1 = *reinterpret_cast<const bf16x8*>(
                &v_s[(jd * 16 + lr) * 72 + 32 + kg * 8]);
            oa[jd] = __builtin_amdgcn_mfma_f32_16x16x32_bf16(pf0, vf0, oa[jd], 0, 0, 0);
            oa[jd] = __builtin_amdgcn_mfma_f32_16x16x32_bf16(pf1, vf1, oa[jd], 0, 0, 0);
        }
        __builtin_amdgcn_s_setprio(0);
    }

    // ---- normalize + store context (B, S, H*hd) bf16 ----
    const int b = bh / NHEADS, h = bh % NHEADS;
    #pragma unroll
    for (int q = 0; q < 4; ++q) {
        const float inv = 1.0f / l_acc[q];
        const int s = q0 + kg * 4 + q;
        #pragma unroll
        for (int jd = 0; jd < 4; ++jd)
            Cctx[(size_t)(b * SEQ + s) * DMODEL + h * HDIM + jd * 16 + lr] =
                to_bf16(oa[jd][q] * inv);
    }
}

// ---------------------------------------------------------------------------
extern "C" void kernel_launch(void* const* d_in, const int* in_sizes, int n_in,
                              void* d_out, int out_size, void* d_ws, size_t ws_size,
                              hipStream_t stream) {
    const float* x  = (const float*)d_in[0];
    const float* Wq = (const float*)d_in[1];
    const float* bq = (const float*)d_in[2];
    const float* Wk = (const float*)d_in[3];
    const float* bk = (const float*)d_in[4];
    const float* Wv = (const float*)d_in[5];
    const float* bv = (const float*)d_in[6];
    const float* Wo = (const float*)d_in[7];
    const float* bo = (const float*)d_in[8];
    float* out = (float*)d_out;

    const size_t MD = (size_t)MROWS * DMODEL;    // 3,145,728
    const size_t W2 = (size_t)DMODEL * DMODEL;   // 589,824
    unsigned short* u = (unsigned short*)d_ws;
    unsigned short* x_bf   = u;            // bf16 x (M x 768)
    unsigned short* q_bf   = u + MD;       // bf16 Q (B,H,S,hd), pre-scaled
    unsigned short* k_bf   = u + 2 * MD;   // bf16 K (B,H,S,hd)
    unsigned short* vt_bf  = u + 3 * MD;   // bf16 V^T (B,H,hd,S)
    unsigned short* c_bf   = u + 4 * MD;   // bf16 context (B,S,768)
    unsigned short* wt_all = u + 5 * MD;   // [Wq^T;Wk^T;Wv^T] bf16 (2304 x 768)
    unsigned short* wot    = wt_all + 3 * W2;
    // total: (5*MD + 4*W2)*2B = 36.2 MB

    cvt_all<<<3072 + 4 * 576, 256, 0, stream>>>(x, Wq, Wk, Wv, Wo,
                                                x_bf, wt_all, wot);

    dim3 gq(3 * DMODEL / 128, MROWS / 128);   // (18, 32) = 576 blocks
    gemm_qkv<<<gq, 256, 0, stream>>>(x_bf, wt_all, bq, bk, bv, q_bf, k_bf, vt_bf);

    flash_mfma<<<768, 256, 0, stream>>>(q_bf, k_bf, vt_bf, c_bf);

    dim3 go(DMODEL / 64, MROWS / 64);         // (12, 64) = 768 blocks, 3/CU
    gemm_out<<<go, 256, 0, stream>>>(c_bf, wot, bo, out);
}